// Round 12
// baseline (173.022 us; speedup 1.0000x reference)
//
#include <hip/hip_runtime.h>

// B=8, T=2048, C=1024, H=64.  Reference: softmax over QUERY axis (dim=1),
// no 1/sqrt(d) scale.  out[t,h] = sum_{s<=t} exp(q_t.k_s)/D_s * v[s,h],
// D_s = sum_{t>=s} exp(q_t.k_s).
// Split-bf16 (hi+lo, 3-term) MFMA for qkv GEMM and QK dots (~fp32 accuracy);
// plain bf16 for V and P in PV (~0.4% rel).
//
// Round-12: EVERYTHING in MFMA-fragment-coalesced layouts.  r11 proved W-frag
// coalescing (4KB-stride loads -> 1KB bursts) was the big lever (62->43us).
// Now qkv's epilogue writes Q/K (hi/lo) and V in fragment order too, so
// stats/out load every fragment as a single contiguous 1KB burst: no staging
// LDS, no in-loop barriers (out keeps only the wave-private wa transpose).
//
// Fragment unit (16 rows x 32 k-cols): lane l = quad*16+lr holds
// row = lr, cols = quad*8..+7.  FQ/FK: [b][tblk(128)][kc(2)][lane][8].
// VF: [b][hblk(4)][sc(64)][lane][8] (n=h rows, k=s cols).

typedef __attribute__((ext_vector_type(8))) short bf16x8;
typedef __attribute__((ext_vector_type(4))) float f32x4;
typedef unsigned short u16;

#define MFMA(a, b, c) __builtin_amdgcn_mfma_f32_16x16x32_bf16((a), (b), (c), 0, 0, 0)

__device__ __forceinline__ u16 f2bf(float x) {           // RNE fp32 -> bf16
    unsigned u = __float_as_uint(x);
    u += 0x7fff + ((u >> 16) & 1);
    return (u16)(u >> 16);
}
__device__ __forceinline__ float bf2f(u16 h) {
    return __uint_as_float(((unsigned)h) << 16);
}

// ws byte offsets
#define WH_OFF  0u
#define WL_OFF  (WH_OFF + 192u*1024u*2u)
#define FQH_OFF (WL_OFF + 192u*1024u*2u)
#define FQL_OFF (FQH_OFF + 2u*1024u*1024u)
#define FKH_OFF (FQL_OFF + 2u*1024u*1024u)
#define FKL_OFF (FKH_OFF + 2u*1024u*1024u)
#define VF_OFF  (FKL_OFF + 2u*1024u*1024u)
#define DD_OFF  (VF_OFF + 2u*1024u*1024u)   // fp32 [B][T]

// ---------------------------------------------------------------------------
// W pre-split into fragment-coalesced layout (r11 verbatim).
// ---------------------------------------------------------------------------
__global__ __launch_bounds__(128) void wsplit_kernel(
    const float* __restrict__ Wk, const float* __restrict__ Wq,
    const float* __restrict__ Wv, u16* __restrict__ FWH, u16* __restrict__ FWL)
{
    const int n = blockIdx.x;                 // 0..191
    const int nblk = n >> 4, lr = n & 15;
    const float* src = (n < 64) ? (Wq + (long)n * 1024)
                     : (n < 128) ? (Wk + (long)(n - 64) * 1024)
                                 : (Wv + (long)(n - 128) * 1024);
    const int f = threadIdx.x;                // 0..127 fragment id
    const int kc = f >> 2, q = f & 3;
    const float4 f0 = *(const float4*)&src[kc * 32 + q * 8];
    const float4 f1 = *(const float4*)&src[kc * 32 + q * 8 + 4];
    const float vs[8] = {f0.x, f0.y, f0.z, f0.w, f1.x, f1.y, f1.z, f1.w};
    bf16x8 hv, lv;
    #pragma unroll
    for (int j = 0; j < 8; ++j) {
        const u16 h = f2bf(vs[j]);
        hv[j] = (short)h;
        lv[j] = (short)f2bf(vs[j] - bf2f(h));
    }
    const long o = ((long)(nblk * 32 + kc) * 64 + q * 16 + lr) * 8;
    *(bf16x8*)&FWH[o] = hv;
    *(bf16x8*)&FWL[o] = lv;
}

// ---------------------------------------------------------------------------
// qkv (r11 structure, fragment-layout epilogue).  M-tile 64, 512 thr = 8
// waves (2m x 4n).  A-tile dbuf LDS; W frags fragment-coalesced global.
// ---------------------------------------------------------------------------
__global__ __launch_bounds__(512, 2) void qkv_kernel(
    const float* __restrict__ idx, const u16* __restrict__ FWH, const u16* __restrict__ FWL,
    u16* __restrict__ FQH, u16* __restrict__ FQL,
    u16* __restrict__ FKH, u16* __restrict__ FKL, u16* __restrict__ VF)
{
    __shared__ u16 a_l[2][64 * 136];
    const int tid = threadIdx.x;
    const int w = tid >> 6, lr = tid & 15, quad = (tid >> 4) & 3;
    const int lane = tid & 63;
    const int r0 = blockIdx.x * 64;
    const int b = r0 >> 11, t0 = r0 & 2047;
    const int m0 = (w & 1) * 32;
    const int nbb = (w >> 1) * 3;              // nblk base for this wave
    const int sr = tid >> 3, sc = (tid & 7) * 8;   // staging: row, col-start
    const float* arow = &idx[(long)(r0 + sr) * 1024 + sc];

    f32x4 acc[2][3] = {};
    float4 pf0, pf1;

    // prologue: stage chunk 0
    pf0 = *(const float4*)(arow);
    pf1 = *(const float4*)(arow + 4);
    {
        const float vs[8] = {pf0.x, pf0.y, pf0.z, pf0.w, pf1.x, pf1.y, pf1.z, pf1.w};
        bf16x8 hv, lv;
        #pragma unroll
        for (int j = 0; j < 8; ++j) {
            const u16 h = f2bf(vs[j]);
            hv[j] = (short)h;
            lv[j] = (short)f2bf(vs[j] - bf2f(h));
        }
        *(bf16x8*)&a_l[0][sr * 136 + sc]      = hv;
        *(bf16x8*)&a_l[0][sr * 136 + 64 + sc] = lv;
    }
    __syncthreads();

    int p = 0;
    for (int it = 0; it < 16; ++it) {
        const int c0 = it * 64;
        if (it < 15) {   // register prefetch of next A chunk
            pf0 = *(const float4*)(arow + c0 + 64);
            pf1 = *(const float4*)(arow + c0 + 68);
        }

        bf16x8 AH[2][2], AL[2][2];
        #pragma unroll
        for (int mi = 0; mi < 2; ++mi) {
            const int ar = (m0 + mi * 16 + lr) * 136 + quad * 8;
            AH[mi][0] = *(const bf16x8*)&a_l[p][ar];
            AH[mi][1] = *(const bf16x8*)&a_l[p][ar + 32];
            AL[mi][0] = *(const bf16x8*)&a_l[p][ar + 64];
            AL[mi][1] = *(const bf16x8*)&a_l[p][ar + 96];
        }

        #pragma unroll
        for (int nf = 0; nf < 3; ++nf) {
            const long base = ((long)((nbb + nf) * 32 + 2 * it) * 64 + lane) * 8;
            const bf16x8 bh0 = *(const bf16x8*)&FWH[base];
            const bf16x8 bh1 = *(const bf16x8*)&FWH[base + 512];
            const bf16x8 bl0 = *(const bf16x8*)&FWL[base];
            const bf16x8 bl1 = *(const bf16x8*)&FWL[base + 512];
            #pragma unroll
            for (int mi = 0; mi < 2; ++mi) {
                f32x4 c = acc[mi][nf];
                c = MFMA(AH[mi][0], bh0, c);
                c = MFMA(AL[mi][0], bh0, c);
                c = MFMA(AH[mi][0], bl0, c);
                c = MFMA(AH[mi][1], bh1, c);
                c = MFMA(AL[mi][1], bh1, c);
                c = MFMA(AH[mi][1], bl1, c);
                acc[mi][nf] = c;
            }
        }

        if (it < 15) {
            const float vs[8] = {pf0.x, pf0.y, pf0.z, pf0.w, pf1.x, pf1.y, pf1.z, pf1.w};
            bf16x8 hv, lv;
            #pragma unroll
            for (int j = 0; j < 8; ++j) {
                const u16 h = f2bf(vs[j]);
                hv[j] = (short)h;
                lv[j] = (short)f2bf(vs[j] - bf2f(h));
            }
            *(bf16x8*)&a_l[p ^ 1][sr * 136 + sc]      = hv;
            *(bf16x8*)&a_l[p ^ 1][sr * 136 + 64 + sc] = lv;
            __syncthreads();
            p ^= 1;
        }
    }

    // epilogue: C layout col = lane&15 (n), row = quad*4 + reg (m).
    // Write Q/K hi+lo and V hi into fragment-coalesced layouts.
    #pragma unroll
    for (int mi = 0; mi < 2; ++mi) {
        const int tb = t0 + m0 + mi * 16 + quad * 4;     // local t base
        const int tblk = (t0 + m0 + mi * 16) >> 4;
        #pragma unroll
        for (int nf = 0; nf < 3; ++nf) {
            const int n = (nbb + nf) * 16 + lr;
            const f32x4 a = acc[mi][nf];
            if (n < 128) {
                u16* Hd = (n < 64) ? FQH : FKH;
                u16* Ld = (n < 64) ? FQL : FKL;
                const int h = n & 63;
                const int kc = h >> 5;
                const int lsub = 16 * ((h & 31) >> 3);
                const long base = ((long)(b * 128 + tblk) * 2 + kc) * 512 + (h & 7);
                #pragma unroll
                for (int r = 0; r < 4; ++r) {
                    const float v = a[r];
                    const u16 hi = f2bf(v);
                    const u16 lo = f2bf(v - bf2f(hi));
                    const long o = base + (long)(quad * 4 + r + lsub) * 8;
                    Hd[o] = hi; Ld[o] = lo;
                }
            } else {
                const int h = n - 128;
                const int hblk = h >> 4;
                #pragma unroll
                for (int r = 0; r < 4; ++r) {
                    const int t = tb + r;
                    const long o = ((long)(b * 4 + hblk) * 64 + (t >> 5)) * 512
                                 + (long)(16 * ((t & 31) >> 3) + (h & 15)) * 8 + (t & 7);
                    VF[o] = f2bf(a[r]);
                }
            }
        }
    }
}

// ---------------------------------------------------------------------------
// stats: D_s = sum_{t>=s} exp(q_t.k_s).  K B-frags hoisted, Q A-frags per-jt:
// ALL fragment-coalesced 1KB loads.  No staging LDS, no in-loop barriers.
// Grid (144, B): s-tile i, t-chunk c (<=4 t-tiles); atomicAdd partials.
// ---------------------------------------------------------------------------
__global__ __launch_bounds__(256, 4) void stats_kernel(
    const u16* __restrict__ FQH, const u16* __restrict__ FQL,
    const u16* __restrict__ FKH, const u16* __restrict__ FKL,
    float* __restrict__ D)
{
    __shared__ float red[4][64];
    const int tid = threadIdx.x;
    const int w = tid >> 6, lr = tid & 15, quad = (tid >> 4) & 3;
    const int lane = tid & 63;
    const int b = blockIdx.y;
    int x = blockIdx.x, i = 0;
    for (;;) { const int nc = (35 - i) >> 2; if (x < nc) break; x -= nc; ++i; }
    const int s0 = i * 64;
    const int jt0 = i + 4 * x, jt1 = min(jt0 + 4, 32);

    // hoist K B-frags (sblk = i*4+nf, kc 0/1): 16 coalesced 1KB loads
    bf16x8 BH[4][2], BL[4][2];
    #pragma unroll
    for (int nf = 0; nf < 4; ++nf) {
        const long kb = ((long)(b * 128 + i * 4 + nf) * 2) * 512 + lane * 8;
        BH[nf][0] = *(const bf16x8*)&FKH[kb];
        BH[nf][1] = *(const bf16x8*)&FKH[kb + 512];
        BL[nf][0] = *(const bf16x8*)&FKL[kb];
        BL[nf][1] = *(const bf16x8*)&FKL[kb + 512];
    }

    float dsum[4] = {0.f, 0.f, 0.f, 0.f};
    for (int jt = jt0; jt < jt1; ++jt) {
        const long qb = ((long)(b * 128 + jt * 4 + w) * 2) * 512 + lane * 8;
        const bf16x8 ah0 = *(const bf16x8*)&FQH[qb];
        const bf16x8 ah1 = *(const bf16x8*)&FQH[qb + 512];
        const bf16x8 al0 = *(const bf16x8*)&FQL[qb];
        const bf16x8 al1 = *(const bf16x8*)&FQL[qb + 512];
        #pragma unroll
        for (int nf = 0; nf < 4; ++nf) {
            f32x4 cc = {};
            cc = MFMA(ah0, BH[nf][0], cc);
            cc = MFMA(al0, BH[nf][0], cc);
            cc = MFMA(ah0, BL[nf][0], cc);
            cc = MFMA(ah1, BH[nf][1], cc);
            cc = MFMA(al1, BH[nf][1], cc);
            cc = MFMA(ah1, BL[nf][1], cc);

            if (jt > i) {
                dsum[nf] += __expf(cc[0]) + __expf(cc[1]) + __expf(cc[2]) + __expf(cc[3]);
            } else {   // diagonal tile: include t >= s only
                const int sl = nf * 16 + lr;
                #pragma unroll
                for (int r = 0; r < 4; ++r) {
                    const int tl = w * 16 + quad * 4 + r;
                    if (tl >= sl) dsum[nf] += __expf(cc[r]);
                }
            }
        }
    }

    #pragma unroll
    for (int nf = 0; nf < 4; ++nf) {
        dsum[nf] += __shfl_xor(dsum[nf], 16);
        dsum[nf] += __shfl_xor(dsum[nf], 32);
    }
    if (quad == 0) {
        #pragma unroll
        for (int nf = 0; nf < 4; ++nf) red[w][nf * 16 + lr] = dsum[nf];
    }
    __syncthreads();
    if (tid < 64)
        atomicAdd(&D[b * 2048 + s0 + tid],
                  red[0][tid] + red[1][tid] + red[2][tid] + red[3][tid]);
}

// ---------------------------------------------------------------------------
// out: out[t][h] = sum_{s<=t} exp(q_t.k_s)/D_s * v[s][h].  Q A-frags hoisted;
// K/V/D fragment-coalesced loads per s-tile; only LDS = wave-private wa
// (P transpose).  NO in-loop barriers.  Grid (144, B): t-tile i, s-chunk c.
// ---------------------------------------------------------------------------
__global__ __launch_bounds__(256, 4) void out_kernel(
    const u16* __restrict__ FQH, const u16* __restrict__ FQL,
    const u16* __restrict__ FKH, const u16* __restrict__ FKL,
    const u16* __restrict__ VF, const float* __restrict__ D,
    float* __restrict__ out)
{
    __shared__ u16 wa[64 * 72];   // P [t][s], rows padded to 72
    const int tid = threadIdx.x;
    const int w = tid >> 6, lr = tid & 15, quad = (tid >> 4) & 3;
    const int lane = tid & 63;
    const int b = blockIdx.y;
    int x = blockIdx.x, i = 0;
    for (;;) { const int nc = (i + 4) >> 2; if (x < nc) break; x -= nc; ++i; }
    const int t0 = i * 64;
    const int js0 = 4 * x, js1 = min(4 * x + 4, i + 1);

    // hoist Q A-frags (tblk = i*4 + w): 4 coalesced 1KB loads
    const long qb = ((long)(b * 128 + i * 4 + w) * 2) * 512 + lane * 8;
    const bf16x8 qh0 = *(const bf16x8*)&FQH[qb];
    const bf16x8 qh1 = *(const bf16x8*)&FQH[qb + 512];
    const bf16x8 ql0 = *(const bf16x8*)&FQL[qb];
    const bf16x8 ql1 = *(const bf16x8*)&FQL[qb + 512];

    f32x4 oacc[4] = {};
    for (int js = js0; js < js1; ++js) {
        const int s0 = js * 64;
        const bool diag = (js == i);

        // dots: K frags transient per nf (coalesced), D direct
        f32x4 cc[4];
        float rv[4];
        #pragma unroll
        for (int nf = 0; nf < 4; ++nf) {
            const long kb = ((long)(b * 128 + js * 4 + nf) * 2) * 512 + lane * 8;
            const bf16x8 bh0 = *(const bf16x8*)&FKH[kb];
            const bf16x8 bh1 = *(const bf16x8*)&FKH[kb + 512];
            const bf16x8 bl0 = *(const bf16x8*)&FKL[kb];
            const bf16x8 bl1 = *(const bf16x8*)&FKL[kb + 512];
            rv[nf] = D[b * 2048 + s0 + nf * 16 + lr];
            f32x4 c = {};
            c = MFMA(qh0, bh0, c);
            c = MFMA(ql0, bh0, c);
            c = MFMA(qh0, bl0, c);
            c = MFMA(qh1, bh1, c);
            c = MFMA(ql1, bh1, c);
            c = MFMA(qh1, bl1, c);
            cc[nf] = c;
        }

        // V frag burst (coalesced; lands during expf/transpose)
        bf16x8 VB[4][2];
        #pragma unroll
        for (int nf = 0; nf < 4; ++nf) {
            const long vb = ((long)(b * 4 + nf) * 64 + 2 * js) * 512 + lane * 8;
            VB[nf][0] = *(const bf16x8*)&VF[vb];
            VB[nf][1] = *(const bf16x8*)&VF[vb + 512];
        }

        // weights + wave-private transpose
        #pragma unroll
        for (int nf = 0; nf < 4; ++nf) {
            const int sl = nf * 16 + lr;
            const float r_ = 1.0f / rv[nf];
            #pragma unroll
            for (int r = 0; r < 4; ++r) {
                const int tl = w * 16 + quad * 4 + r;   // own wave's strip
                float pv = __expf(cc[nf][r]) * r_;
                if (diag && tl < sl) pv = 0.f;
                wa[tl * 72 + sl] = f2bf(pv);
            }
        }

        // PV
        #pragma unroll
        for (int kk = 0; kk < 2; ++kk) {
            const bf16x8 av = *(const bf16x8*)&wa[(w * 16 + lr) * 72 + kk * 32 + quad * 8];
            #pragma unroll
            for (int nf = 0; nf < 4; ++nf)
                oacc[nf] = MFMA(av, VB[nf][kk], oacc[nf]);
        }
    }

    const bool single = (i < 4);   // one chunk covers the whole row
    #pragma unroll
    for (int nf = 0; nf < 4; ++nf) {
        const int h = nf * 16 + lr;
        #pragma unroll
        for (int r = 0; r < 4; ++r) {
            const int t = t0 + w * 16 + quad * 4 + r;
            const long o = (long)(b * 2048 + t) * 64 + h;
            if (single) out[o] = oacc[nf][r];
            else        atomicAdd(&out[o], oacc[nf][r]);
        }
    }
}

extern "C" void kernel_launch(void* const* d_in, const int* in_sizes, int n_in,
                              void* d_out, int out_size, void* d_ws, size_t ws_size,
                              hipStream_t stream)
{
    const float* idx = (const float*)d_in[0];
    const float* Wk  = (const float*)d_in[1];
    const float* Wq  = (const float*)d_in[2];
    const float* Wv  = (const float*)d_in[3];
    char* ws = (char*)d_ws;
    float* out = (float*)d_out;

    u16* FWH = (u16*)(ws + WH_OFF);  u16* FWL = (u16*)(ws + WL_OFF);
    u16* FQH = (u16*)(ws + FQH_OFF); u16* FQL = (u16*)(ws + FQL_OFF);
    u16* FKH = (u16*)(ws + FKH_OFF); u16* FKL = (u16*)(ws + FKL_OFF);
    u16* VF  = (u16*)(ws + VF_OFF);
    float* Dp = (float*)(ws + DD_OFF);

    hipMemsetAsync(out, 0, (size_t)8 * 2048 * 64 * sizeof(float), stream);
    hipMemsetAsync(Dp, 0, (size_t)8 * 2048 * sizeof(float), stream);

    wsplit_kernel<<<192, 128, 0, stream>>>(Wk, Wq, Wv, FWH, FWL);
    qkv_kernel<<<256, 512, 0, stream>>>(idx, FWH, FWL, FQH, FQL, FKH, FKL, VF);
    stats_kernel<<<dim3(144, 8), 256, 0, stream>>>(FQH, FQL, FKH, FKL, Dp);
    out_kernel<<<dim3(144, 8), 256, 0, stream>>>(FQH, FQL, FKH, FKL, VF, Dp, out);
}

// Round 13
// 166.258 us; speedup vs baseline: 1.0407x; 1.0407x over previous
//
#include <hip/hip_runtime.h>

// B=8, T=2048, C=1024, H=64.  Reference: softmax over QUERY axis (dim=1),
// no 1/sqrt(d) scale.  out[t,h] = sum_{s<=t} exp(q_t.k_s)/D_s * v[s,h],
// D_s = sum_{t>=s} exp(q_t.k_s).
// Split-bf16 (hi+lo, 3-term) MFMA for qkv GEMM and QK dots (~fp32 accuracy);
// plain bf16 for V and P in PV (~0.4% rel).
//
// Round-13: stats STORES P = exp(S) (causal-masked, unnormalized, bf16) in
// MFMA A-fragment layout while accumulating D — out no longer recomputes the
// dots.  vscale folds 1/D_s into the V fragments.  out = pure streaming PV
// GEMM: coalesced P/V fragment loads + 8 MFMA per s-tile, no LDS/barriers/exp.
// P buffer = 67 MB in ws (harness poison shows ws = 256 MB).

typedef __attribute__((ext_vector_type(8))) short bf16x8;
typedef __attribute__((ext_vector_type(4))) float f32x4;
typedef unsigned short u16;

#define MFMA(a, b, c) __builtin_amdgcn_mfma_f32_16x16x32_bf16((a), (b), (c), 0, 0, 0)

__device__ __forceinline__ u16 f2bf(float x) {           // RNE fp32 -> bf16
    unsigned u = __float_as_uint(x);
    u += 0x7fff + ((u >> 16) & 1);
    return (u16)(u >> 16);
}
__device__ __forceinline__ float bf2f(u16 h) {
    return __uint_as_float(((unsigned)h) << 16);
}

// ws byte offsets
#define WH_OFF  0u
#define WL_OFF  (WH_OFF + 192u*1024u*2u)
#define FQH_OFF (WL_OFF + 192u*1024u*2u)
#define FQL_OFF (FQH_OFF + 2u*1024u*1024u)
#define FKH_OFF (FQL_OFF + 2u*1024u*1024u)
#define FKL_OFF (FKH_OFF + 2u*1024u*1024u)
#define VF_OFF  (FKL_OFF + 2u*1024u*1024u)
#define DD_OFF  (VF_OFF + 2u*1024u*1024u)          // fp32 [B][T] = 64 KB
#define PF_OFF  (DD_OFF + 8u*2048u*4u)             // bf16, 67 MB

// ---------------------------------------------------------------------------
// W pre-split into fragment-coalesced layout (r12 verbatim).
// ---------------------------------------------------------------------------
__global__ __launch_bounds__(128) void wsplit_kernel(
    const float* __restrict__ Wk, const float* __restrict__ Wq,
    const float* __restrict__ Wv, u16* __restrict__ FWH, u16* __restrict__ FWL)
{
    const int n = blockIdx.x;                 // 0..191
    const int nblk = n >> 4, lr = n & 15;
    const float* src = (n < 64) ? (Wq + (long)n * 1024)
                     : (n < 128) ? (Wk + (long)(n - 64) * 1024)
                                 : (Wv + (long)(n - 128) * 1024);
    const int f = threadIdx.x;                // 0..127 fragment id
    const int kc = f >> 2, q = f & 3;
    const float4 f0 = *(const float4*)&src[kc * 32 + q * 8];
    const float4 f1 = *(const float4*)&src[kc * 32 + q * 8 + 4];
    const float vs[8] = {f0.x, f0.y, f0.z, f0.w, f1.x, f1.y, f1.z, f1.w};
    bf16x8 hv, lv;
    #pragma unroll
    for (int j = 0; j < 8; ++j) {
        const u16 h = f2bf(vs[j]);
        hv[j] = (short)h;
        lv[j] = (short)f2bf(vs[j] - bf2f(h));
    }
    const long o = ((long)(nblk * 32 + kc) * 64 + q * 16 + lr) * 8;
    *(bf16x8*)&FWH[o] = hv;
    *(bf16x8*)&FWL[o] = lv;
}

// ---------------------------------------------------------------------------
// qkv (r12 verbatim).  M-tile 64, 512 thr = 8 waves (2m x 4n).  A-tile dbuf
// LDS; W frags fragment-coalesced global; epilogue writes fragment layouts.
// ---------------------------------------------------------------------------
__global__ __launch_bounds__(512, 2) void qkv_kernel(
    const float* __restrict__ idx, const u16* __restrict__ FWH, const u16* __restrict__ FWL,
    u16* __restrict__ FQH, u16* __restrict__ FQL,
    u16* __restrict__ FKH, u16* __restrict__ FKL, u16* __restrict__ VF)
{
    __shared__ u16 a_l[2][64 * 136];
    const int tid = threadIdx.x;
    const int w = tid >> 6, lr = tid & 15, quad = (tid >> 4) & 3;
    const int lane = tid & 63;
    const int r0 = blockIdx.x * 64;
    const int b = r0 >> 11, t0 = r0 & 2047;
    const int m0 = (w & 1) * 32;
    const int nbb = (w >> 1) * 3;
    const int sr = tid >> 3, sc = (tid & 7) * 8;
    const float* arow = &idx[(long)(r0 + sr) * 1024 + sc];

    f32x4 acc[2][3] = {};
    float4 pf0, pf1;

    pf0 = *(const float4*)(arow);
    pf1 = *(const float4*)(arow + 4);
    {
        const float vs[8] = {pf0.x, pf0.y, pf0.z, pf0.w, pf1.x, pf1.y, pf1.z, pf1.w};
        bf16x8 hv, lv;
        #pragma unroll
        for (int j = 0; j < 8; ++j) {
            const u16 h = f2bf(vs[j]);
            hv[j] = (short)h;
            lv[j] = (short)f2bf(vs[j] - bf2f(h));
        }
        *(bf16x8*)&a_l[0][sr * 136 + sc]      = hv;
        *(bf16x8*)&a_l[0][sr * 136 + 64 + sc] = lv;
    }
    __syncthreads();

    int p = 0;
    for (int it = 0; it < 16; ++it) {
        const int c0 = it * 64;
        if (it < 15) {
            pf0 = *(const float4*)(arow + c0 + 64);
            pf1 = *(const float4*)(arow + c0 + 68);
        }

        bf16x8 AH[2][2], AL[2][2];
        #pragma unroll
        for (int mi = 0; mi < 2; ++mi) {
            const int ar = (m0 + mi * 16 + lr) * 136 + quad * 8;
            AH[mi][0] = *(const bf16x8*)&a_l[p][ar];
            AH[mi][1] = *(const bf16x8*)&a_l[p][ar + 32];
            AL[mi][0] = *(const bf16x8*)&a_l[p][ar + 64];
            AL[mi][1] = *(const bf16x8*)&a_l[p][ar + 96];
        }

        #pragma unroll
        for (int nf = 0; nf < 3; ++nf) {
            const long base = ((long)((nbb + nf) * 32 + 2 * it) * 64 + lane) * 8;
            const bf16x8 bh0 = *(const bf16x8*)&FWH[base];
            const bf16x8 bh1 = *(const bf16x8*)&FWH[base + 512];
            const bf16x8 bl0 = *(const bf16x8*)&FWL[base];
            const bf16x8 bl1 = *(const bf16x8*)&FWL[base + 512];
            #pragma unroll
            for (int mi = 0; mi < 2; ++mi) {
                f32x4 c = acc[mi][nf];
                c = MFMA(AH[mi][0], bh0, c);
                c = MFMA(AL[mi][0], bh0, c);
                c = MFMA(AH[mi][0], bl0, c);
                c = MFMA(AH[mi][1], bh1, c);
                c = MFMA(AL[mi][1], bh1, c);
                c = MFMA(AH[mi][1], bl1, c);
                acc[mi][nf] = c;
            }
        }

        if (it < 15) {
            const float vs[8] = {pf0.x, pf0.y, pf0.z, pf0.w, pf1.x, pf1.y, pf1.z, pf1.w};
            bf16x8 hv, lv;
            #pragma unroll
            for (int j = 0; j < 8; ++j) {
                const u16 h = f2bf(vs[j]);
                hv[j] = (short)h;
                lv[j] = (short)f2bf(vs[j] - bf2f(h));
            }
            *(bf16x8*)&a_l[p ^ 1][sr * 136 + sc]      = hv;
            *(bf16x8*)&a_l[p ^ 1][sr * 136 + 64 + sc] = lv;
            __syncthreads();
            p ^= 1;
        }
    }

    #pragma unroll
    for (int mi = 0; mi < 2; ++mi) {
        const int tb = t0 + m0 + mi * 16 + quad * 4;
        const int tblk = (t0 + m0 + mi * 16) >> 4;
        #pragma unroll
        for (int nf = 0; nf < 3; ++nf) {
            const int n = (nbb + nf) * 16 + lr;
            const f32x4 a = acc[mi][nf];
            if (n < 128) {
                u16* Hd = (n < 64) ? FQH : FKH;
                u16* Ld = (n < 64) ? FQL : FKL;
                const int h = n & 63;
                const int kc = h >> 5;
                const int lsub = 16 * ((h & 31) >> 3);
                const long base = ((long)(b * 128 + tblk) * 2 + kc) * 512 + (h & 7);
                #pragma unroll
                for (int r = 0; r < 4; ++r) {
                    const float v = a[r];
                    const u16 hi = f2bf(v);
                    const u16 lo = f2bf(v - bf2f(hi));
                    const long o = base + (long)(quad * 4 + r + lsub) * 8;
                    Hd[o] = hi; Ld[o] = lo;
                }
            } else {
                const int h = n - 128;
                const int hblk = h >> 4;
                #pragma unroll
                for (int r = 0; r < 4; ++r) {
                    const int t = tb + r;
                    const long o = ((long)(b * 4 + hblk) * 64 + (t >> 5)) * 512
                                 + (long)(16 * ((t & 31) >> 3) + (h & 15)) * 8 + (t & 7);
                    VF[o] = f2bf(a[r]);
                }
            }
        }
    }
}

// ---------------------------------------------------------------------------
// stats: D_s = sum_{t>=s} exp(q_t.k_s)  AND stores P = exp (masked, bf16)
// into A-fragment layout PF[b][tblk][kc=s/32][lane][8].  K B-frags hoisted,
// Q A-frags per-jt (all fragment-coalesced 1KB loads).  No staging LDS.
// Grid (144, B): s-tile i, t-chunk c (<=4 t-tiles); atomicAdd partials.
// ---------------------------------------------------------------------------
__global__ __launch_bounds__(256, 4) void stats_kernel(
    const u16* __restrict__ FQH, const u16* __restrict__ FQL,
    const u16* __restrict__ FKH, const u16* __restrict__ FKL,
    u16* __restrict__ PF, float* __restrict__ D)
{
    __shared__ float red[4][64];
    const int tid = threadIdx.x;
    const int w = tid >> 6, lr = tid & 15, quad = (tid >> 4) & 3;
    const int lane = tid & 63;
    const int b = blockIdx.y;
    int x = blockIdx.x, i = 0;
    for (;;) { const int nc = (35 - i) >> 2; if (x < nc) break; x -= nc; ++i; }
    const int s0 = i * 64;
    const int jt0 = i + 4 * x, jt1 = min(jt0 + 4, 32);

    bf16x8 BH[4][2], BL[4][2];
    #pragma unroll
    for (int nf = 0; nf < 4; ++nf) {
        const long kb = ((long)(b * 128 + i * 4 + nf) * 2) * 512 + lane * 8;
        BH[nf][0] = *(const bf16x8*)&FKH[kb];
        BH[nf][1] = *(const bf16x8*)&FKH[kb + 512];
        BL[nf][0] = *(const bf16x8*)&FKL[kb];
        BL[nf][1] = *(const bf16x8*)&FKL[kb + 512];
    }

    float dsum[4] = {0.f, 0.f, 0.f, 0.f};
    for (int jt = jt0; jt < jt1; ++jt) {
        const long qb = ((long)(b * 128 + jt * 4 + w) * 2) * 512 + lane * 8;
        const bf16x8 ah0 = *(const bf16x8*)&FQH[qb];
        const bf16x8 ah1 = *(const bf16x8*)&FQH[qb + 512];
        const bf16x8 al0 = *(const bf16x8*)&FQL[qb];
        const bf16x8 al1 = *(const bf16x8*)&FQL[qb + 512];
        const bool diag = (jt == i);
        #pragma unroll
        for (int nf = 0; nf < 4; ++nf) {
            f32x4 cc = {};
            cc = MFMA(ah0, BH[nf][0], cc);
            cc = MFMA(al0, BH[nf][0], cc);
            cc = MFMA(ah0, BL[nf][0], cc);
            cc = MFMA(ah1, BH[nf][1], cc);
            cc = MFMA(al1, BH[nf][1], cc);
            cc = MFMA(ah1, BL[nf][1], cc);

            // P store base: t = jt*64 + w*16 + quad*4 + r, s = i*64 + nf*16 + lr
            const long pbase = ((long)(b * 128 + jt * 4 + w) * 64 + i * 2 + (nf >> 1)) * 512
                             + (long)(((nf & 1) * 2 + (lr >> 3)) * 16) * 8 + (lr & 7);
            const int sl = nf * 16 + lr;
            #pragma unroll
            for (int r = 0; r < 4; ++r) {
                float ev = __expf(cc[r]);
                if (diag && (w * 16 + quad * 4 + r < sl)) ev = 0.f;
                dsum[nf] += ev;
                PF[pbase + (long)(quad * 4 + r) * 8] = f2bf(ev);
            }
        }
    }

    #pragma unroll
    for (int nf = 0; nf < 4; ++nf) {
        dsum[nf] += __shfl_xor(dsum[nf], 16);
        dsum[nf] += __shfl_xor(dsum[nf], 32);
    }
    if (quad == 0) {
        #pragma unroll
        for (int nf = 0; nf < 4; ++nf) red[w][nf * 16 + lr] = dsum[nf];
    }
    __syncthreads();
    if (tid < 64)
        atomicAdd(&D[b * 2048 + s0 + tid],
                  red[0][tid] + red[1][tid] + red[2][tid] + red[3][tid]);
}

// ---------------------------------------------------------------------------
// vscale: VF (B-fragment layout) *= 1/D[s].  Entry (b,hblk,kc,lane,j) has
// s = kc*32 + (lane>>4)*8 + j  (j consecutive in s).
// ---------------------------------------------------------------------------
__global__ __launch_bounds__(256) void vscale_kernel(
    u16* __restrict__ VF, const float* __restrict__ D)
{
    const int g = blockIdx.x * 256 + threadIdx.x;   // 131072 threads x 8 u16
    const long e = (long)g * 8;
    const int lane = (int)((e >> 3) & 63);
    const int kc   = (int)((e >> 9) & 63);
    const int b    = (int)(e >> 17);
    const int s = kc * 32 + (lane >> 4) * 8;
    const float4 d0 = *(const float4*)&D[b * 2048 + s];
    const float4 d1 = *(const float4*)&D[b * 2048 + s + 4];
    const float dv[8] = {d0.x, d0.y, d0.z, d0.w, d1.x, d1.y, d1.z, d1.w};
    bf16x8 vv = *(bf16x8*)&VF[e];
    bf16x8 ov;
    #pragma unroll
    for (int j = 0; j < 8; ++j)
        ov[j] = (short)f2bf(bf2f((u16)vv[j]) / dv[j]);
    *(bf16x8*)&VF[e] = ov;
}

// ---------------------------------------------------------------------------
// out: pure streaming PV GEMM.  out[t][h] = sum_{s<=t} P[t][s] * Vtilde[s][h].
// Per s-tile: 2 P A-frag loads + 8 V B-frag loads + 8 MFMA.  No LDS, no
// barriers, no exp.  Grid (80, B): t-tile i, s-chunk c (<=8 s-tiles).
// ---------------------------------------------------------------------------
__global__ __launch_bounds__(256, 4) void out_kernel(
    const u16* __restrict__ PF, const u16* __restrict__ VF,
    float* __restrict__ out)
{
    const int tid = threadIdx.x;
    const int w = tid >> 6, lr = tid & 15, quad = (tid >> 4) & 3;
    const int lane = tid & 63;
    const int b = blockIdx.y;
    int x = blockIdx.x, i = 0;
    for (;;) { const int nc = (i + 8) >> 3; if (x < nc) break; x -= nc; ++i; }
    const int t0 = i * 64;
    const int js0 = 8 * x, js1 = min(8 * x + 8, i + 1);
    const int tblk = i * 4 + w;

    f32x4 oacc[4] = {};
    for (int js = js0; js < js1; ++js) {
        const long pb = ((long)(b * 128 + tblk) * 64 + 2 * js) * 512 + lane * 8;
        const bf16x8 a0 = *(const bf16x8*)&PF[pb];
        const bf16x8 a1 = *(const bf16x8*)&PF[pb + 512];
        #pragma unroll
        for (int nf = 0; nf < 4; ++nf) {
            const long vb = ((long)(b * 4 + nf) * 64 + 2 * js) * 512 + lane * 8;
            const bf16x8 v0 = *(const bf16x8*)&VF[vb];
            const bf16x8 v1 = *(const bf16x8*)&VF[vb + 512];
            oacc[nf] = MFMA(a0, v0, oacc[nf]);
            oacc[nf] = MFMA(a1, v1, oacc[nf]);
        }
    }

    const bool single = (i < 8);   // one chunk covers the whole row
    #pragma unroll
    for (int nf = 0; nf < 4; ++nf) {
        const int h = nf * 16 + lr;
        #pragma unroll
        for (int r = 0; r < 4; ++r) {
            const int t = t0 + w * 16 + quad * 4 + r;
            const long o = (long)(b * 2048 + t) * 64 + h;
            if (single) out[o] = oacc[nf][r];
            else        atomicAdd(&out[o], oacc[nf][r]);
        }
    }
}

extern "C" void kernel_launch(void* const* d_in, const int* in_sizes, int n_in,
                              void* d_out, int out_size, void* d_ws, size_t ws_size,
                              hipStream_t stream)
{
    const float* idx = (const float*)d_in[0];
    const float* Wk  = (const float*)d_in[1];
    const float* Wq  = (const float*)d_in[2];
    const float* Wv  = (const float*)d_in[3];
    char* ws = (char*)d_ws;
    float* out = (float*)d_out;

    u16* FWH = (u16*)(ws + WH_OFF);  u16* FWL = (u16*)(ws + WL_OFF);
    u16* FQH = (u16*)(ws + FQH_OFF); u16* FQL = (u16*)(ws + FQL_OFF);
    u16* FKH = (u16*)(ws + FKH_OFF); u16* FKL = (u16*)(ws + FKL_OFF);
    u16* VF  = (u16*)(ws + VF_OFF);
    float* Dp = (float*)(ws + DD_OFF);
    u16* PF  = (u16*)(ws + PF_OFF);

    hipMemsetAsync(out, 0, (size_t)8 * 2048 * 64 * sizeof(float), stream);
    hipMemsetAsync(Dp, 0, (size_t)8 * 2048 * sizeof(float), stream);

    wsplit_kernel<<<192, 128, 0, stream>>>(Wk, Wq, Wv, FWH, FWL);
    qkv_kernel<<<256, 512, 0, stream>>>(idx, FWH, FWL, FQH, FQL, FKH, FKL, VF);
    stats_kernel<<<dim3(144, 8), 256, 0, stream>>>(FQH, FQL, FKH, FKL, PF, Dp);
    vscale_kernel<<<512, 256, 0, stream>>>(VF, Dp);
    out_kernel<<<dim3(80, 8), 256, 0, stream>>>(PF, VF, out);
}